// Round 1
// baseline (1121.641 us; speedup 1.0000x reference)
//
#include <hip/hip_runtime.h>
#include <hip/hip_bf16.h>

#define N_NODES 12000
#define N_EDGES 384000
#define F_INN   128
#define DLAT    64
#define BN_EPS  1e-4f

__device__ __forceinline__ float sigmoidf(float x) { return 1.0f / (1.0f + __expf(-x)); }

// ---------------- CSR build ----------------
__global__ void k_init(int* cnt, int* cur, int n) {
    int i = blockIdx.x * blockDim.x + threadIdx.x;
    if (i < n) { cnt[i] = 0; cur[i] = 0; }
}

__global__ void k_count(const int* dst, int* cnt, int e) {
    int i = blockIdx.x * blockDim.x + threadIdx.x;
    if (i < e) atomicAdd(&cnt[dst[i]], 1);
}

// single-block exclusive scan of cnt[n] -> offs[n+1]
__global__ void k_scan(const int* cnt, int* offs, int n) {
    __shared__ int buf[1024];
    __shared__ int carry;
    int tid = threadIdx.x;
    if (tid == 0) { carry = 0; offs[0] = 0; }
    __syncthreads();
    for (int base = 0; base < n; base += 1024) {
        int i = base + tid;
        int v = (i < n) ? cnt[i] : 0;
        buf[tid] = v;
        __syncthreads();
        for (int o = 1; o < 1024; o <<= 1) {
            int t = (tid >= o) ? buf[tid - o] : 0;
            __syncthreads();
            buf[tid] += t;
            __syncthreads();
        }
        if (i < n) offs[i + 1] = carry + buf[tid];
        __syncthreads();
        if (tid == 0) carry += buf[1023];
        __syncthreads();
    }
}

__global__ void k_dis(const int* cnt, float* dis, int n) {
    int i = blockIdx.x * blockDim.x + threadIdx.x;
    if (i < n) dis[i] = rsqrtf((float)(cnt[i] + 1));   // deg = in-degree + self-loop
}

__global__ void k_scatter(const int* src, const int* dst, const int* offs, int* cur,
                          int* ssrc, int e) {
    int i = blockIdx.x * blockDim.x + threadIdx.x;
    if (i < e) {
        int d = dst[i];
        int p = atomicAdd(&cur[d], 1);
        ssrc[offs[d] + p] = src[i];
    }
}

// ---------------- dense X[n,K] @ [Wa|Wb][K,M] -> out[n,M] ----------------
// W staged in LDS (K*M <= 8192 floats). blockDim=256, rows/block = 256/M.
__global__ void k_mm(const float* __restrict__ X, int n, int K,
                     const float* __restrict__ Wa, int Ma,
                     const float* __restrict__ Wb, int Mb,
                     float* __restrict__ out) {
    __shared__ float Wl[8192];
    int M = Ma + Mb;
    for (int idx = threadIdx.x; idx < K * M; idx += blockDim.x) {
        int k = idx / M, m = idx % M;
        Wl[idx] = (m < Ma) ? Wa[k * Ma + m] : Wb[k * Mb + (m - Ma)];
    }
    __syncthreads();
    int rpb = blockDim.x / M;
    int r = blockIdx.x * rpb + threadIdx.x / M;
    int m = threadIdx.x % M;
    if (r >= n) return;
    const float* xr = X + (size_t)r * K;
    float acc = 0.f;
    for (int k = 0; k < K; k++) acc += xr[k] * Wl[k * M + m];
    out[(size_t)r * M + m] = acc;
}

// ---------------- GCN aggregation + bias + sigmoid ----------------
// out[i,f] = sigmoid( dis[i]*( h[i,f]*dis[i] + sum_edges h[s,f]*dis[s] ) + b[f] )
__global__ void k_agg(const float* __restrict__ h, const float* __restrict__ dis,
                      const int* __restrict__ offs, const int* __restrict__ ssrc,
                      const float* __restrict__ ba, const float* __restrict__ bb, int Ma,
                      float* __restrict__ out, int dim, int n) {
    int t = blockIdx.x * blockDim.x + threadIdx.x;
    int node = t / dim;
    if (node >= n) return;
    int f = t - node * dim;
    float di = dis[node];
    float acc = h[(size_t)node * dim + f] * di;
    int e0 = offs[node], e1 = offs[node + 1];
    int j = e0;
    for (; j + 3 < e1; j += 4) {
        int s0 = ssrc[j], s1 = ssrc[j + 1], s2 = ssrc[j + 2], s3 = ssrc[j + 3];
        acc += h[(size_t)s0 * dim + f] * dis[s0];
        acc += h[(size_t)s1 * dim + f] * dis[s1];
        acc += h[(size_t)s2 * dim + f] * dis[s2];
        acc += h[(size_t)s3 * dim + f] * dis[s3];
    }
    for (; j < e1; j++) {
        int s = ssrc[j];
        acc += h[(size_t)s * dim + f] * dis[s];
    }
    float bias = (f < Ma) ? ba[f] : bb[f - Ma];
    out[(size_t)node * dim + f] = sigmoidf(acc * di + bias);
}

// ---------------- BatchNorm (training-mode batch stats) ----------------
__global__ void k_stats(const float* __restrict__ act, int dim, int n,
                        float* __restrict__ mu, float* __restrict__ var) {
    int c = blockIdx.x;
    float s = 0.f, s2 = 0.f;
    for (int r = threadIdx.x; r < n; r += blockDim.x) {
        float v = act[(size_t)r * dim + c];
        s += v; s2 += v * v;
    }
    __shared__ float sh[512];
    sh[threadIdx.x] = s; sh[256 + threadIdx.x] = s2;
    __syncthreads();
    for (int o = 128; o > 0; o >>= 1) {
        if (threadIdx.x < o) {
            sh[threadIdx.x] += sh[threadIdx.x + o];
            sh[256 + threadIdx.x] += sh[256 + threadIdx.x + o];
        }
        __syncthreads();
    }
    if (threadIdx.x == 0) {
        float m = sh[0] / n;
        mu[c] = m;
        var[c] = sh[256] / n - m * m;
    }
}

__global__ void k_bnapply(const float* __restrict__ in, float* __restrict__ out,
                          const float* __restrict__ mu, const float* __restrict__ var,
                          const float* __restrict__ g, const float* __restrict__ be,
                          int dim, size_t total) {
    size_t i = (size_t)blockIdx.x * blockDim.x + threadIdx.x;
    if (i >= total) return;
    int f = (int)(i % dim);
    out[i] = (in[i] - mu[f]) * rsqrtf(var[f] + BN_EPS) * g[f] + be[f];
}

// fused BN(mean)/BN(logstd) + reparameterization: z = noise*exp(logstd)+mean
__global__ void k_z(const float* __restrict__ act2, const float* __restrict__ noise,
                    const float* __restrict__ mu, const float* __restrict__ var,
                    const float* __restrict__ gm, const float* __restrict__ bem,
                    const float* __restrict__ gs, const float* __restrict__ bes,
                    float* __restrict__ z, int n) {
    int i = blockIdx.x * blockDim.x + threadIdx.x;
    if (i >= n * DLAT) return;
    int row = i >> 6, j = i & 63;
    const float* ar = act2 + (size_t)row * 128;
    float m  = (ar[j]      - mu[j])      * rsqrtf(var[j]      + BN_EPS) * gm[j] + bem[j];
    float ls = (ar[j + 64] - mu[j + 64]) * rsqrtf(var[j + 64] + BN_EPS) * gs[j] + bes[j];
    z[i] = noise[i] * __expf(ls) + m;
}

// ---------------- decoder MLP: leakyrelu(z@Dw1+Db1)@Dw2+Db2 ----------------
__global__ void k_dec(const float* __restrict__ z,
                      const float* __restrict__ W1, const float* __restrict__ B1,
                      const float* __restrict__ W2, const float* __restrict__ B2,
                      float* __restrict__ out, int n) {
    __shared__ float w1[64 * 64];
    __shared__ float w2[64 * 128];
    __shared__ float hl[4 * 64];
    for (int i = threadIdx.x; i < 4096; i += 256) w1[i] = W1[i];
    for (int i = threadIdx.x; i < 8192; i += 256) w2[i] = W2[i];
    __syncthreads();
    int r0 = blockIdx.x * 4;
    {
        int r = threadIdx.x / 64, hc = threadIdx.x % 64;
        int row = r0 + r;
        float acc = B1[hc];
        const float* zr = z + (size_t)row * 64;
        for (int k = 0; k < 64; k++) acc += zr[k] * w1[k * 64 + hc];
        hl[r * 64 + hc] = acc > 0.f ? acc : 0.01f * acc;
    }
    __syncthreads();
    for (int pass = 0; pass < 2; pass++) {
        int r = pass * 2 + threadIdx.x / 128;
        int oc = threadIdx.x % 128;
        int row = r0 + r;
        float acc = B2[oc];
        for (int k = 0; k < 64; k++) acc += hl[r * 64 + k] * w2[k * 128 + oc];
        out[(size_t)row * 128 + oc] = acc;
    }
}

// ---------------- A_pred = sigmoid(z @ z^T), 64x64 tiles ----------------
#define TN 188   // ceil(12000/64)
__global__ __launch_bounds__(256) void k_apred(const float* __restrict__ z,
                                               float* __restrict__ out, int n) {
    __shared__ float zi[4096];  // k-major: zi[k*64 + r]
    __shared__ float zj[4096];
    int bi = blockIdx.x % TN, bj = blockIdx.x / TN;
    int i0 = bi * 64, j0 = bj * 64;
    int t = threadIdx.x;
    int lr = t >> 2, kq = t & 3;  // row-in-tile 0..63, 16-float chunk 0..3
    {
        int row = i0 + lr;
        const float4* s = (const float4*)(z + (size_t)row * 64 + kq * 16);
        float4 v0, v1, v2, v3;
        if (row < n) { v0 = s[0]; v1 = s[1]; v2 = s[2]; v3 = s[3]; }
        else { v0 = v1 = v2 = v3 = make_float4(0.f, 0.f, 0.f, 0.f); }
        int k0 = kq * 16;
        float4 vs[4] = {v0, v1, v2, v3};
        for (int q = 0; q < 4; q++) {
            int k = k0 + q * 4;
            zi[(k + 0) * 64 + lr] = vs[q].x;
            zi[(k + 1) * 64 + lr] = vs[q].y;
            zi[(k + 2) * 64 + lr] = vs[q].z;
            zi[(k + 3) * 64 + lr] = vs[q].w;
        }
    }
    {
        int row = j0 + lr;
        const float4* s = (const float4*)(z + (size_t)row * 64 + kq * 16);
        float4 v0, v1, v2, v3;
        if (row < n) { v0 = s[0]; v1 = s[1]; v2 = s[2]; v3 = s[3]; }
        else { v0 = v1 = v2 = v3 = make_float4(0.f, 0.f, 0.f, 0.f); }
        int k0 = kq * 16;
        float4 vs[4] = {v0, v1, v2, v3};
        for (int q = 0; q < 4; q++) {
            int k = k0 + q * 4;
            zj[(k + 0) * 64 + lr] = vs[q].x;
            zj[(k + 1) * 64 + lr] = vs[q].y;
            zj[(k + 2) * 64 + lr] = vs[q].z;
            zj[(k + 3) * 64 + lr] = vs[q].w;
        }
    }
    __syncthreads();

    int tx = t & 15, ty = t >> 4;
    int c0 = tx * 4, r0 = ty * 4;
    float acc[4][4] = {};
    for (int k = 0; k < 64; k++) {
        float4 a = *(const float4*)&zi[k * 64 + r0];
        float4 b = *(const float4*)&zj[k * 64 + c0];
        acc[0][0] += a.x * b.x; acc[0][1] += a.x * b.y; acc[0][2] += a.x * b.z; acc[0][3] += a.x * b.w;
        acc[1][0] += a.y * b.x; acc[1][1] += a.y * b.y; acc[1][2] += a.y * b.z; acc[1][3] += a.y * b.w;
        acc[2][0] += a.z * b.x; acc[2][1] += a.z * b.y; acc[2][2] += a.z * b.z; acc[2][3] += a.z * b.w;
        acc[3][0] += a.w * b.x; acc[3][1] += a.w * b.y; acc[3][2] += a.w * b.z; acc[3][3] += a.w * b.w;
    }
    int col = j0 + c0;
    if (col < n) {
        for (int i = 0; i < 4; i++) {
            int row = i0 + r0 + i;
            if (row >= n) break;
            float4 o;
            o.x = sigmoidf(acc[i][0]);
            o.y = sigmoidf(acc[i][1]);
            o.z = sigmoidf(acc[i][2]);
            o.w = sigmoidf(acc[i][3]);
            *(float4*)&out[(size_t)row * n + col] = o;
        }
    }
}

extern "C" void kernel_launch(void* const* d_in, const int* in_sizes, int n_in,
                              void* d_out, int out_size, void* d_ws, size_t ws_size,
                              hipStream_t stream) {
    const float* x     = (const float*)d_in[0];
    const int*   src   = (const int*)d_in[1];
    const int*   dst   = (const int*)d_in[2];
    const float* noise = (const float*)d_in[4];
    const float* W0  = (const float*)d_in[5];
    const float* b0  = (const float*)d_in[6];
    const float* g0  = (const float*)d_in[7];
    const float* be0 = (const float*)d_in[8];
    const float* Wm  = (const float*)d_in[9];
    const float* bm  = (const float*)d_in[10];
    const float* gm  = (const float*)d_in[11];
    const float* bem = (const float*)d_in[12];
    const float* Ws  = (const float*)d_in[13];
    const float* bs  = (const float*)d_in[14];
    const float* gs  = (const float*)d_in[15];
    const float* bes = (const float*)d_in[16];
    const float* Dw1 = (const float*)d_in[17];
    const float* Db1 = (const float*)d_in[18];
    const float* Dw2 = (const float*)d_in[19];
    const float* Db2 = (const float*)d_in[20];
    float* out = (float*)d_out;

    const int n = N_NODES, e = N_EDGES;

    // workspace layout (4-byte words)
    int*   cnt  = (int*)d_ws;
    int*   offs = (int*)d_ws + 12032;
    int*   cur  = (int*)d_ws + 24064;
    int*   ssrc = (int*)d_ws + 36096;
    float* dis  = (float*)d_ws + 420096;
    float* mu   = (float*)d_ws + 432128;
    float* var  = (float*)d_ws + 432384;
    float* bufA = (float*)d_ws + 432640;            // [N,128]
    float* bufB = bufA + (size_t)N_NODES * 128;     // [N,128]
    float* zbuf = bufB;                             // z overlays bufB after h2 is dead

    // CSR build
    k_init<<<(n + 255) / 256, 256, 0, stream>>>(cnt, cur, n);
    k_count<<<(e + 255) / 256, 256, 0, stream>>>(dst, cnt, e);
    k_scan<<<1, 1024, 0, stream>>>(cnt, offs, n);
    k_dis<<<(n + 255) / 256, 256, 0, stream>>>(cnt, dis, n);
    k_scatter<<<(e + 255) / 256, 256, 0, stream>>>(src, dst, offs, cur, ssrc, e);

    // layer 1: h0 = x @ W0 ; aggregate ; sigmoid ; BN -> hidden (bufA)
    k_mm<<<n / 4, 256, 0, stream>>>(x, n, F_INN, W0, DLAT, nullptr, 0, bufA);
    k_agg<<<(n * DLAT) / 256, 256, 0, stream>>>(bufA, dis, offs, ssrc, b0, nullptr, DLAT,
                                                bufB, DLAT, n);
    k_stats<<<DLAT, 256, 0, stream>>>(bufB, DLAT, n, mu, var);
    k_bnapply<<<(n * DLAT) / 256, 256, 0, stream>>>(bufB, bufA, mu, var, g0, be0, DLAT,
                                                    (size_t)n * DLAT);

    // layers 2+3 fused: h2 = hidden @ [Wm|Ws] ; aggregate 128 ; sigmoid
    k_mm<<<n / 2, 256, 0, stream>>>(bufA, n, DLAT, Wm, DLAT, Ws, DLAT, bufB);
    k_agg<<<(n * 128) / 256, 256, 0, stream>>>(bufB, dis, offs, ssrc, bm, bs, DLAT,
                                               bufA, 128, n);
    k_stats<<<128, 256, 0, stream>>>(bufA, 128, n, mu, var);

    // BN(mean), BN(logstd), reparameterize -> z (bufB)
    k_z<<<(n * DLAT) / 256, 256, 0, stream>>>(bufA, noise, mu, var, gm, bem, gs, bes,
                                              zbuf, n);

    // decoder -> out[0 : N*F_IN)
    k_dec<<<n / 4, 256, 0, stream>>>(zbuf, Dw1, Db1, Dw2, Db2, out, n);

    // A_pred -> out[N*F_IN : )
    k_apred<<<TN * TN, 256, 0, stream>>>(zbuf, out + (size_t)n * F_INN, n);
}

// Round 2
// 1006.808 us; speedup vs baseline: 1.1141x; 1.1141x over previous
//
#include <hip/hip_runtime.h>
#include <hip/hip_bf16.h>

#define N_NODES 12000
#define N_EDGES 384000
#define F_INN   128
#define DLAT    64
#define BN_EPS  1e-4f

__device__ __forceinline__ float sigmoidf(float x) { return 1.0f / (1.0f + __expf(-x)); }

// ---------------- CSR build ----------------
__global__ void k_init(int* cnt, int* cur, int n) {
    int i = blockIdx.x * blockDim.x + threadIdx.x;
    if (i < n) { cnt[i] = 0; cur[i] = 0; }
}

__global__ void k_count(const int* dst, int* cnt, int e) {
    int i = blockIdx.x * blockDim.x + threadIdx.x;
    if (i < e) atomicAdd(&cnt[dst[i]], 1);
}

// single-block scan: 1024 threads x 12 elems each (covers 12288 >= 12000)
// also computes dis[i] = rsqrt(deg+1)
__global__ void k_scan(const int* __restrict__ cnt, int* __restrict__ offs,
                       float* __restrict__ dis, int n) {
    __shared__ int wsum[16];
    int tid = threadIdx.x;
    int base = tid * 12;
    int v[12];
    int s = 0;
#pragma unroll
    for (int q = 0; q < 12; q++) {
        int i = base + q;
        v[q] = (i < n) ? cnt[i] : 0;
        s += v[q];
        if (i < n) dis[i] = rsqrtf((float)(v[q] + 1));
    }
    int lane = tid & 63, w = tid >> 6;
    int ps = s;
#pragma unroll
    for (int o = 1; o < 64; o <<= 1) {
        int t2 = __shfl_up(ps, o, 64);
        if (lane >= o) ps += t2;
    }
    if (lane == 63) wsum[w] = ps;
    __syncthreads();
    if (tid == 0) {
        int acc = 0;
        for (int i = 0; i < 16; i++) { int t2 = wsum[i]; wsum[i] = acc; acc += t2; }
    }
    __syncthreads();
    int acc = wsum[w] + ps - s;   // exclusive prefix of this thread's first element
#pragma unroll
    for (int q = 0; q < 12; q++) {
        int i = base + q;
        if (i < n) offs[i] = acc;
        acc += v[q];
        if (i == n - 1) offs[n] = acc;
    }
}

__global__ void k_scatter(const int* src, const int* dst, const int* offs, int* cur,
                          int* ssrc, int e) {
    int i = blockIdx.x * blockDim.x + threadIdx.x;
    if (i < e) {
        int d = dst[i];
        int p = atomicAdd(&cur[d], 1);
        ssrc[offs[d] + p] = src[i];
    }
}

// ---------------- dense X[n,K] @ [Wa|Wb][K,M] -> out[n,M] ----------------
__global__ void k_mm(const float* __restrict__ X, int n, int K,
                     const float* __restrict__ Wa, int Ma,
                     const float* __restrict__ Wb, int Mb,
                     float* __restrict__ out) {
    __shared__ float Wl[8192];
    int M = Ma + Mb;
    for (int idx = threadIdx.x; idx < K * M; idx += blockDim.x) {
        int k = idx / M, m = idx % M;
        Wl[idx] = (m < Ma) ? Wa[k * Ma + m] : Wb[k * Mb + (m - Ma)];
    }
    __syncthreads();
    int rpb = blockDim.x / M;
    int r = blockIdx.x * rpb + threadIdx.x / M;
    int m = threadIdx.x % M;
    if (r >= n) return;
    const float* xr = X + (size_t)r * K;
    float acc = 0.f;
    for (int k = 0; k < K; k++) acc += xr[k] * Wl[k * M + m];
    out[(size_t)r * M + m] = acc;
}

// ---------------- GCN aggregation + bias + sigmoid ----------------
__global__ void k_agg(const float* __restrict__ h, const float* __restrict__ dis,
                      const int* __restrict__ offs, const int* __restrict__ ssrc,
                      const float* __restrict__ ba, const float* __restrict__ bb, int Ma,
                      float* __restrict__ out, int dim, int n) {
    int t = blockIdx.x * blockDim.x + threadIdx.x;
    int node = t / dim;
    if (node >= n) return;
    int f = t - node * dim;
    float di = dis[node];
    float acc = h[(size_t)node * dim + f] * di;
    int e0 = offs[node], e1 = offs[node + 1];
    int j = e0;
    for (; j + 3 < e1; j += 4) {
        int s0 = ssrc[j], s1 = ssrc[j + 1], s2 = ssrc[j + 2], s3 = ssrc[j + 3];
        acc += h[(size_t)s0 * dim + f] * dis[s0];
        acc += h[(size_t)s1 * dim + f] * dis[s1];
        acc += h[(size_t)s2 * dim + f] * dis[s2];
        acc += h[(size_t)s3 * dim + f] * dis[s3];
    }
    for (; j < e1; j++) {
        int s = ssrc[j];
        acc += h[(size_t)s * dim + f] * dis[s];
    }
    float bias = (f < Ma) ? ba[f] : bb[f - Ma];
    out[(size_t)node * dim + f] = sigmoidf(acc * di + bias);
}

// ---------------- BatchNorm stats (two-stage, coalesced) ----------------
#define STATS_BLOCKS 64
__global__ void k_stats1(const float* __restrict__ act, int dim, int n,
                         float* __restrict__ part) {
    int rpb = 256 / dim;                 // rows per iteration per block (4 or 2)
    int c = threadIdx.x % dim;
    int rloc = threadIdx.x / dim;
    float s = 0.f, s2 = 0.f;
    for (int r = blockIdx.x * rpb + rloc; r < n; r += STATS_BLOCKS * rpb) {
        float v = act[(size_t)r * dim + c];
        s += v; s2 += v * v;
    }
    __shared__ float sh[512];
    sh[threadIdx.x] = s; sh[256 + threadIdx.x] = s2;
    __syncthreads();
    if (rloc == 0) {
        for (int q = 1; q < rpb; q++) {
            s += sh[q * dim + c];
            s2 += sh[256 + q * dim + c];
        }
        part[(size_t)(blockIdx.x * dim + c) * 2] = s;
        part[(size_t)(blockIdx.x * dim + c) * 2 + 1] = s2;
    }
}

__global__ void k_stats2(const float* __restrict__ part, int dim, int n,
                         float* __restrict__ mu, float* __restrict__ var) {
    int c = threadIdx.x;
    if (c >= dim) return;
    float s = 0.f, s2 = 0.f;
    for (int q = 0; q < STATS_BLOCKS; q++) {
        s += part[(size_t)(q * dim + c) * 2];
        s2 += part[(size_t)(q * dim + c) * 2 + 1];
    }
    float m = s / n;
    mu[c] = m;
    var[c] = s2 / n - m * m;
}

__global__ void k_bnapply(const float* __restrict__ in, float* __restrict__ out,
                          const float* __restrict__ mu, const float* __restrict__ var,
                          const float* __restrict__ g, const float* __restrict__ be,
                          int dim, size_t total) {
    size_t i = (size_t)blockIdx.x * blockDim.x + threadIdx.x;
    if (i >= total) return;
    int f = (int)(i % dim);
    out[i] = (in[i] - mu[f]) * rsqrtf(var[f] + BN_EPS) * g[f] + be[f];
}

// fused BN(mean)/BN(logstd) + reparameterization
__global__ void k_z(const float* __restrict__ act2, const float* __restrict__ noise,
                    const float* __restrict__ mu, const float* __restrict__ var,
                    const float* __restrict__ gm, const float* __restrict__ bem,
                    const float* __restrict__ gs, const float* __restrict__ bes,
                    float* __restrict__ z, int n) {
    int i = blockIdx.x * blockDim.x + threadIdx.x;
    if (i >= n * DLAT) return;
    int row = i >> 6, j = i & 63;
    const float* ar = act2 + (size_t)row * 128;
    float m  = (ar[j]      - mu[j])      * rsqrtf(var[j]      + BN_EPS) * gm[j] + bem[j];
    float ls = (ar[j + 64] - mu[j + 64]) * rsqrtf(var[j + 64] + BN_EPS) * gs[j] + bes[j];
    z[i] = noise[i] * __expf(ls) + m;
}

// ---------------- decoder MLP, 16 rows per block ----------------
__global__ void k_dec(const float* __restrict__ z,
                      const float* __restrict__ W1, const float* __restrict__ B1,
                      const float* __restrict__ W2, const float* __restrict__ B2,
                      float* __restrict__ out, int n) {
    __shared__ float w1[64 * 64];
    __shared__ float w2[64 * 128];
    __shared__ float zl[16 * 64];
    __shared__ float hl[16 * 64];
    int t = threadIdx.x;
    int row0 = blockIdx.x * 16;
    {
        const float4* W14 = (const float4*)W1;
        const float4* W24 = (const float4*)W2;
        for (int i = t; i < 1024; i += 256) ((float4*)w1)[i] = W14[i];
        for (int i = t; i < 2048; i += 256) ((float4*)w2)[i] = W24[i];
        ((float4*)zl)[t] = ((const float4*)(z + (size_t)row0 * 64))[t];
    }
    __syncthreads();
    {
        int hc = t & 63, rg = t >> 6;      // 4 rows per thread
        float a0 = B1[hc], a1 = a0, a2 = a0, a3 = a0;
        int rb = rg * 4;
        for (int k = 0; k < 64; k++) {
            float wv = w1[k * 64 + hc];
            a0 += zl[(rb + 0) * 64 + k] * wv;
            a1 += zl[(rb + 1) * 64 + k] * wv;
            a2 += zl[(rb + 2) * 64 + k] * wv;
            a3 += zl[(rb + 3) * 64 + k] * wv;
        }
        hl[(rb + 0) * 64 + hc] = a0 > 0.f ? a0 : 0.01f * a0;
        hl[(rb + 1) * 64 + hc] = a1 > 0.f ? a1 : 0.01f * a1;
        hl[(rb + 2) * 64 + hc] = a2 > 0.f ? a2 : 0.01f * a2;
        hl[(rb + 3) * 64 + hc] = a3 > 0.f ? a3 : 0.01f * a3;
    }
    __syncthreads();
    {
        int oc = t & 127, rg = t >> 7;     // 8 rows per thread
        float o[8];
#pragma unroll
        for (int i = 0; i < 8; i++) o[i] = B2[oc];
        int rb = rg * 8;
        for (int k = 0; k < 64; k++) {
            float wv = w2[k * 128 + oc];
#pragma unroll
            for (int i = 0; i < 8; i++) o[i] += hl[(rb + i) * 64 + k] * wv;
        }
#pragma unroll
        for (int i = 0; i < 8; i++)
            out[(size_t)(row0 + rb + i) * 128 + oc] = o[i];
    }
}

// ---------------- A_pred = sigmoid(z @ z^T), symmetric 128x128 tiles ----------------
#define TN2 94   // ceil(12000/128)
__global__ __launch_bounds__(256, 2) void k_apred(const float* __restrict__ z,
                                                  float* __restrict__ out, int n) {
    __shared__ float zi[64 * 128];  // k-major: zi[k*128 + r]
    __shared__ float zj[64 * 128];
    int b = blockIdx.x;
    // decode triangular (bi <= bj)
    float ff = (float)(2 * TN2 + 1);
    int bi = (int)((ff - sqrtf(ff * ff - 8.0f * (float)b)) * 0.5f);
    while (bi > 0 && b < bi * TN2 - bi * (bi - 1) / 2) bi--;
    while (b >= (bi + 1) * TN2 - (bi + 1) * bi / 2) bi++;
    int bj = bi + (b - (bi * TN2 - bi * (bi - 1) / 2));
    int i0 = bi * 128, j0 = bj * 128;

    int t = threadIdx.x;
    int r = t >> 1, half = t & 1;   // r: 0..127, half selects k in [0,32) or [32,64)
    {
        int row = i0 + r;
        const float4* s4 = (const float4*)(z + (size_t)row * 64 + half * 32);
#pragma unroll
        for (int q = 0; q < 8; q++) {
            float4 v = (row < n) ? s4[q] : make_float4(0.f, 0.f, 0.f, 0.f);
            int k = half * 32 + q * 4;
            zi[(k + 0) * 128 + r] = v.x;
            zi[(k + 1) * 128 + r] = v.y;
            zi[(k + 2) * 128 + r] = v.z;
            zi[(k + 3) * 128 + r] = v.w;
        }
        row = j0 + r;
        const float4* s4b = (const float4*)(z + (size_t)row * 64 + half * 32);
#pragma unroll
        for (int q = 0; q < 8; q++) {
            float4 v = (row < n) ? s4b[q] : make_float4(0.f, 0.f, 0.f, 0.f);
            int k = half * 32 + q * 4;
            zj[(k + 0) * 128 + r] = v.x;
            zj[(k + 1) * 128 + r] = v.y;
            zj[(k + 2) * 128 + r] = v.z;
            zj[(k + 3) * 128 + r] = v.w;
        }
    }
    __syncthreads();

    int tx = t & 15, ty = t >> 4;
    int c0 = tx * 8, r0 = ty * 8;
    float acc[8][8] = {};
    for (int k = 0; k < 64; k++) {
        float4 a0 = *(const float4*)&zi[k * 128 + r0];
        float4 a1 = *(const float4*)&zi[k * 128 + r0 + 4];
        float4 b0 = *(const float4*)&zj[k * 128 + c0];
        float4 b1 = *(const float4*)&zj[k * 128 + c0 + 4];
        float av[8] = {a0.x, a0.y, a0.z, a0.w, a1.x, a1.y, a1.z, a1.w};
        float bv[8] = {b0.x, b0.y, b0.z, b0.w, b1.x, b1.y, b1.z, b1.w};
#pragma unroll
        for (int i = 0; i < 8; i++)
#pragma unroll
            for (int j = 0; j < 8; j++) acc[i][j] += av[i] * bv[j];
    }
#pragma unroll
    for (int i = 0; i < 8; i++)
#pragma unroll
        for (int j = 0; j < 8; j++) acc[i][j] = sigmoidf(acc[i][j]);

    // normal tile write
#pragma unroll
    for (int i = 0; i < 8; i++) {
        int row = i0 + r0 + i;
        if (row >= n) continue;
        if (j0 + c0 + 4 <= n)
            *(float4*)&out[(size_t)row * n + j0 + c0] =
                make_float4(acc[i][0], acc[i][1], acc[i][2], acc[i][3]);
        if (j0 + c0 + 8 <= n)
            *(float4*)&out[(size_t)row * n + j0 + c0 + 4] =
                make_float4(acc[i][4], acc[i][5], acc[i][6], acc[i][7]);
    }
    // mirrored tile write (transpose)
    if (bi != bj) {
#pragma unroll
        for (int j = 0; j < 8; j++) {
            int row = j0 + c0 + j;
            if (row >= n) continue;
            if (i0 + r0 + 4 <= n)
                *(float4*)&out[(size_t)row * n + i0 + r0] =
                    make_float4(acc[0][j], acc[1][j], acc[2][j], acc[3][j]);
            if (i0 + r0 + 8 <= n)
                *(float4*)&out[(size_t)row * n + i0 + r0 + 4] =
                    make_float4(acc[4][j], acc[5][j], acc[6][j], acc[7][j]);
        }
    }
}

extern "C" void kernel_launch(void* const* d_in, const int* in_sizes, int n_in,
                              void* d_out, int out_size, void* d_ws, size_t ws_size,
                              hipStream_t stream) {
    const float* x     = (const float*)d_in[0];
    const int*   src   = (const int*)d_in[1];
    const int*   dst   = (const int*)d_in[2];
    const float* noise = (const float*)d_in[4];
    const float* W0  = (const float*)d_in[5];
    const float* b0  = (const float*)d_in[6];
    const float* g0  = (const float*)d_in[7];
    const float* be0 = (const float*)d_in[8];
    const float* Wm  = (const float*)d_in[9];
    const float* bm  = (const float*)d_in[10];
    const float* gm  = (const float*)d_in[11];
    const float* bem = (const float*)d_in[12];
    const float* Ws  = (const float*)d_in[13];
    const float* bs  = (const float*)d_in[14];
    const float* gs  = (const float*)d_in[15];
    const float* bes = (const float*)d_in[16];
    const float* Dw1 = (const float*)d_in[17];
    const float* Db1 = (const float*)d_in[18];
    const float* Dw2 = (const float*)d_in[19];
    const float* Db2 = (const float*)d_in[20];
    float* out = (float*)d_out;

    const int n = N_NODES, e = N_EDGES;

    // workspace layout (4-byte words)
    int*   cnt  = (int*)d_ws;                       // 12000
    int*   offs = (int*)d_ws + 12032;               // 12001
    int*   cur  = (int*)d_ws + 24064;               // 12000
    int*   ssrc = (int*)d_ws + 36096;               // 384000
    float* dis  = (float*)d_ws + 420096;            // 12000
    float* mu   = (float*)d_ws + 432128;            // 128
    float* var  = (float*)d_ws + 432384;            // 128
    float* part = (float*)d_ws + 432640;            // 64*128*2 = 16384
    float* bufA = (float*)d_ws + 449024;            // [N,128]
    float* bufB = bufA + (size_t)N_NODES * 128;     // [N,128]
    float* zbuf = bufB;

    // CSR build
    k_init<<<(n + 255) / 256, 256, 0, stream>>>(cnt, cur, n);
    k_count<<<(e + 255) / 256, 256, 0, stream>>>(dst, cnt, e);
    k_scan<<<1, 1024, 0, stream>>>(cnt, offs, dis, n);
    k_scatter<<<(e + 255) / 256, 256, 0, stream>>>(src, dst, offs, cur, ssrc, e);

    // layer 1
    k_mm<<<n / 4, 256, 0, stream>>>(x, n, F_INN, W0, DLAT, nullptr, 0, bufA);
    k_agg<<<(n * DLAT) / 256, 256, 0, stream>>>(bufA, dis, offs, ssrc, b0, nullptr, DLAT,
                                                bufB, DLAT, n);
    k_stats1<<<STATS_BLOCKS, 256, 0, stream>>>(bufB, DLAT, n, part);
    k_stats2<<<1, 64, 0, stream>>>(part, DLAT, n, mu, var);
    k_bnapply<<<(n * DLAT) / 256, 256, 0, stream>>>(bufB, bufA, mu, var, g0, be0, DLAT,
                                                    (size_t)n * DLAT);

    // layers 2+3 fused
    k_mm<<<n / 2, 256, 0, stream>>>(bufA, n, DLAT, Wm, DLAT, Ws, DLAT, bufB);
    k_agg<<<(n * 128) / 256, 256, 0, stream>>>(bufB, dis, offs, ssrc, bm, bs, DLAT,
                                               bufA, 128, n);
    k_stats1<<<STATS_BLOCKS, 256, 0, stream>>>(bufA, 128, n, part);
    k_stats2<<<1, 128, 0, stream>>>(part, 128, n, mu, var);

    // BN + reparameterize -> z
    k_z<<<(n * DLAT) / 256, 256, 0, stream>>>(bufA, noise, mu, var, gm, bem, gs, bes,
                                              zbuf, n);

    // decoder
    k_dec<<<n / 16, 256, 0, stream>>>(zbuf, Dw1, Db1, Dw2, Db2, out, n);

    // A_pred (symmetric)
    k_apred<<<TN2 * (TN2 + 1) / 2, 256, 0, stream>>>(zbuf, out + (size_t)n * F_INN, n);
}